// Round 9
// baseline (3771.199 us; speedup 1.0000x reference)
//
#include <hip/hip_runtime.h>
#include <cstdint>

typedef _Float16 f16;
typedef _Float16 f16x8 __attribute__((ext_vector_type(8)));
typedef float f32x4 __attribute__((ext_vector_type(4)));
typedef unsigned int u32;

#define DEV __device__ __forceinline__

DEV void gll16(const void* g, void* l) {
  __builtin_amdgcn_global_load_lds((const __attribute__((address_space(1))) u32*)g,
                                   (__attribute__((address_space(3))) u32*)l, 16, 0, 0);
}
// LLC-coherent (cross-XCD) helpers — proven R6/R7
DEV f32x4 ld16c(const void* p) {
  f32x4 r;
  asm volatile("global_load_dwordx4 %0, %1, off sc0 sc1" : "=&v"(r) : "v"(p) : "memory");
  return r;
}
DEV float ld4p(const void* p) {
  float r;
  asm volatile("global_load_dword %0, %1, off" : "=&v"(r) : "v"(p) : "memory");
  return r;
}
DEV void st4c(void* p, float v) {
  asm volatile("global_store_dword %0, %1, off sc0 sc1" :: "v"(p), "v"(v) : "memory");
}
DEV void vmwait() {
  asm volatile("s_waitcnt vmcnt(0)" ::: "memory");
  __builtin_amdgcn_sched_barrier(0);
}
DEV u32 inc_rlx(u32* p) { return __hip_atomic_fetch_add(p, 1u, __ATOMIC_RELAXED, __HIP_MEMORY_SCOPE_AGENT); }

DEV float wsum(float v) {
#pragma unroll
  for (int o = 32; o; o >>= 1) v += __shfl_xor(v, o);
  return v;
}

// ---- fused residual+l_project(+LN) / final-LN reducer over one 64-row tile ----
// 4 waves x 16 rows; each wave owns a full 512-col row (64 lanes x 8).
template <int NP, int MODE>  // MODE 0: resproj (x update, opt LN -> act); 1: final LN -> outp
DEV void reduce_tile(int m0, const float* r1, const float* r2, const float* r3, const float* r4,
                     const float* bias, float rw, const float* g, const float* bsh,
                     float* x, f16* act, float* outp, float* ssqz, int applyLN) {
  const int wid = threadIdx.x >> 6, lane = threadIdx.x & 63, cbase = lane * 8;
  for (int t = 0; t < 16; t++) {
    const int row = m0 + wid * 16 + t;
    const size_t rb = (size_t)row * 512 + cbase;
    f32x4 a0 = ld16c(r1 + rb), a1 = ld16c(r1 + rb + 4);
    f32x4 b0, b1, c0v, c1v, d0, d1;
    if (NP == 4) {
      b0 = ld16c(r2 + rb); b1 = ld16c(r2 + rb + 4);
      c0v = ld16c(r3 + rb); c1v = ld16c(r3 + rb + 4);
      d0 = ld16c(r4 + rb); d1 = ld16c(r4 + rb + 4);
    }
    float xs[8]; float xt = 0.f;
    if (MODE == 0) {
      const float* xrowp = x + (size_t)row * 512;
#pragma unroll
      for (int j = 0; j < 8; j++) {
        int c = cbase + j;
        xs[j] = (c < 511) ? ld4p(xrowp + 1 + c) : 0.f;
      }
      xt = ld4p(xrowp);
    }
    vmwait();
    float y[8];
#pragma unroll
    for (int j = 0; j < 4; j++) {
      y[j] = a0[j]; y[4 + j] = a1[j];
      if (NP == 4) { y[j] += b0[j] + c0v[j] + d0[j]; y[4 + j] += b1[j] + c1v[j] + d1[j]; }
    }
    float lss = 0.f;
#pragma unroll
    for (int j = 0; j < 8; j++) {
      int c = cbase + j;
      y[j] = (c < 511) ? (y[j] + bias[c]) : 0.f;
      lss += y[j] * y[j];
    }
    float ss = wsum(lss);
    if (MODE == 1) {
      float lsu = 0.f;
#pragma unroll
      for (int j = 0; j < 8; j++) lsu += y[j];
      float su = wsum(lsu);
      float mu = su * (1.f / 511.f);
      float var = ss * (1.f / 511.f) - mu * mu;
      float inv = rsqrtf(var + 1e-5f);
      float n[8], lsn = 0.f;
#pragma unroll
      for (int j = 0; j < 8; j++) {
        int c = cbase + j;
        n[j] = (c < 511) ? ((y[j] - mu) * inv * g[c] + bsh[c]) : 0.f;
        lsn += n[j] * n[j];
      }
      float t2 = sqrtf(wsum(lsn) + 1.f);
      float* orow = outp + (size_t)row * 512;
      if (lane == 0) orow[0] = t2;
#pragma unroll
      for (int j = 0; j < 8; j++) { int c = cbase + j; if (c < 511) orow[1 + c] = n[j]; }
    } else {
      float tax = sqrtf(ss + 1.f);
      float u[8], lsu = 0.f, lsu2 = 0.f;
#pragma unroll
      for (int j = 0; j < 8; j++) {
        int c = cbase + j;
        u[j] = (c < 511) ? (xs[j] + rw * y[j]) : 0.f;
        lsu += u[j]; lsu2 += u[j] * u[j];
      }
      float su = wsum(lsu), su2 = wsum(lsu2);
      float ut = xt + rw * tax;
      float scp = rsqrtf(fmaxf(ut * ut - su2, 1e-6f));
      float nxt = ut * scp;
      float nx[8];
#pragma unroll
      for (int j = 0; j < 8; j++) nx[j] = u[j] * scp;
      float* xrow = x + (size_t)row * 512;
      if (lane == 0) xrow[0] = nxt;
#pragma unroll
      for (int j = 0; j < 8; j++) { int c = cbase + j; if (c < 511) xrow[1 + c] = nx[j]; }
      if (NP == 4 && lane == 0) ssqz[row] = 0.f;
      f16* arow = act + (size_t)row * 512;
      if (applyLN) {
        float mu = su * scp * (1.f / 511.f);
        float var = su2 * scp * scp * (1.f / 511.f) - mu * mu;
        float inv = rsqrtf(var + 1e-5f);
        float n[8], lsn = 0.f;
#pragma unroll
        for (int j = 0; j < 8; j++) {
          int c = cbase + j;
          n[j] = (c < 511) ? ((nx[j] - mu) * inv * g[c] + bsh[c]) : 0.f;
          lsn += n[j] * n[j];
        }
        float t2 = sqrtf(wsum(lsn) + 1.f);
        if (lane == 0) arow[0] = (f16)t2;
#pragma unroll
        for (int j = 0; j < 8; j++) { int c = cbase + j; if (c < 511) arow[1 + c] = (f16)n[j]; }
      } else {
        if (lane == 0) arow[0] = (f16)nxt;
#pragma unroll
        for (int j = 0; j < 8; j++) { int c = cbase + j; if (c < 511) arow[1 + c] = (f16)nx[j]; }
      }
    }
  }
}

// ---------------- GEMM: BK=64, dbuf LDS, raw s_barrier + counted vmcnt ----------------
// EPI 1: QKV -> qhat/khat/vT.  EPI 2: gelu -> H1 + atomicAdd ssq.
// EPI 3: Wpr partial (sc0sc1) + rank-1 on tz0 + last-arriver res2.  (KZ=4)
// EPI 4: Wo full (sc0sc1) + last-arriver res1.  EPI 5: Wfin (sc0sc1) + last-arriver final.
template <int BM, int BN, int KZ, int EPI>
__global__ __launch_bounds__((BM == 128) ? 512 : 256)
void k_gemm(const f16* __restrict__ A, const f16* __restrict__ B,
            int lda, int ldb, int klen, int GM,
            float* __restrict__ O1, float* __restrict__ O2,
            float* __restrict__ O3, float* __restrict__ O4, int ldc,
            const float* __restrict__ c0, const float* __restrict__ c1,
            const float* __restrict__ c2, float* __restrict__ ssq,
            f16* __restrict__ H1, f16* __restrict__ H2, f16* __restrict__ H3,
            float* __restrict__ x, f16* __restrict__ act, float* __restrict__ outp,
            const float* __restrict__ lng, const float* __restrict__ lnb,
            const float* __restrict__ rwv, int li, int applyLN, u32* __restrict__ cnt) {
  constexpr int NW = (BM == 128) ? 8 : 4;
  constexpr int WM = (BM == 128) ? 4 : 2;
  constexpr int FN = BN / ((NW / WM) * 16);
  const int tid = threadIdx.x, wid = tid >> 6, lane = tid & 63;
  const int l15 = lane & 15, l4 = lane >> 4;
  const int wm = wid % WM, wn = wid / WM;
  const int nwg = gridDim.x;
  int lin = blockIdx.x;
  int wg = (lin & 7) * (nwg >> 3) + (lin >> 3);
  int tn = wg / (GM * KZ);
  int rem = wg - tn * (GM * KZ);
  int tm = rem / KZ, tz = rem - (rem / KZ) * KZ;
  const int m0 = tm * BM, n0 = tn * BN, kbeg = tz * klen, ksteps = klen / 64;
  __shared__ __align__(16) char SM[(BM + BN) * 256];
  __shared__ int sred;
  f32x4 acc[2][FN];
#pragma unroll
  for (int i = 0; i < 2; i++)
#pragma unroll
    for (int j = 0; j < FN; j++) acc[i][j] = (f32x4){0.f, 0.f, 0.f, 0.f};
  const size_t ldab = (size_t)lda * 2, ldbb = (size_t)ldb * 2;
  const int swz = ((lane & 7) ^ (lane >> 3)) * 16;
  const char* Ab = (const char*)A + (size_t)(m0 + (lane >> 3)) * ldab + swz + (size_t)kbeg * 2;
  const char* Bb = (const char*)B + (size_t)(n0 + (lane >> 3)) * ldbb + swz + (size_t)kbeg * 2;
  auto stage = [&](int buf, int ks) {
    char* da = SM + buf * (BM * 128);
    char* db = SM + 2 * BM * 128 + buf * (BN * 128);
    for (int i = wid; i < BM / 8; i += NW)
      gll16(Ab + (size_t)(i * 8) * ldab + (size_t)ks * 128, da + i * 1024);
    for (int i = wid; i < BN / 8; i += NW)
      gll16(Bb + (size_t)(i * 8) * ldbb + (size_t)ks * 128, db + i * 1024);
  };
  stage(0, 0);
  asm volatile("s_waitcnt vmcnt(0)" ::: "memory");
  __builtin_amdgcn_s_barrier();
  __builtin_amdgcn_sched_barrier(0);
  int cur = 0;
  for (int ks = 0; ks < ksteps; ks++) {
    const bool more = (ks + 1 < ksteps);
    if (more) {
      stage(cur ^ 1, ks + 1);
      asm volatile("s_waitcnt vmcnt(4)" ::: "memory");
    } else {
      asm volatile("s_waitcnt vmcnt(0)" ::: "memory");
    }
    __builtin_amdgcn_s_barrier();
    __builtin_amdgcn_sched_barrier(0);
    const f16* sA = (const f16*)(SM + cur * (BM * 128));
    const f16* sB = (const f16*)(SM + 2 * BM * 128 + cur * (BN * 128));
#pragma unroll
    for (int kk = 0; kk < 2; kk++) {
      f16x8 af[2], bf[FN];
#pragma unroll
      for (int i = 0; i < 2; i++) {
        int row = wm * 32 + i * 16 + l15;
        af[i] = *(const f16x8*)(sA + row * 64 + (((kk * 4 + l4) ^ (l15 & 7)) * 8));
      }
#pragma unroll
      for (int j = 0; j < FN; j++) {
        int row = wn * (FN * 16) + j * 16 + l15;
        bf[j] = *(const f16x8*)(sB + row * 64 + (((kk * 4 + l4) ^ (l15 & 7)) * 8));
      }
#pragma unroll
      for (int i = 0; i < 2; i++)
#pragma unroll
        for (int j = 0; j < FN; j++)
          acc[i][j] = __builtin_amdgcn_mfma_f32_16x16x32_f16(af[i], bf[j], acc[i][j], 0, 0, 0);
    }
    __builtin_amdgcn_sched_barrier(0);
    __builtin_amdgcn_s_barrier();
    cur ^= 1;
  }
  // ---- epilogues ----
  if (EPI == 1) {
    const int cb = (n0 >> 6) + wn;
    const int typ = cb >> 3, h = cb & 7;
    const float* bb = (typ == 0) ? c0 : (typ == 1) ? c1 : c2;
    float bj[FN];
#pragma unroll
    for (int j = 0; j < FN; j++) bj[j] = bb[h * 64 + j * 16 + l15];
    const float qs = (typ == 0) ? 0.25f : 1.0f;
#pragma unroll
    for (int i = 0; i < 2; i++) {
#pragma unroll
      for (int r = 0; r < 4; r++) {
        float y[FN], ss = 0.f;
#pragma unroll
        for (int j = 0; j < FN; j++) { y[j] = acc[i][j][r] + bj[j]; ss += y[j] * y[j]; }
        ss += __shfl_xor(ss, 1); ss += __shfl_xor(ss, 2);
        ss += __shfl_xor(ss, 4); ss += __shfl_xor(ss, 8);
        float t = sqrtf(ss + 1.f);
        int row = m0 + wm * 32 + i * 16 + l4 * 4 + r;
        int b = row >> 10, s = row & 1023, bh = b * 8 + h;
        if (typ < 2) {
          f16* dst = typ ? H2 : H1;
          size_t base = ((size_t)bh * 1024 + s) * 88;
#pragma unroll
          for (int j = 0; j < FN; j++) dst[base + j * 16 + l15] = (f16)(qs * y[j]);
          if (l15 == 0) dst[base + 64] = (f16)(qs * t);
        } else {
#pragma unroll
          for (int j = 0; j < FN; j++)
            H3[((size_t)bh * 80 + j * 16 + l15) * 1024 + s] = (f16)y[j];
          if (l15 == 0) H3[((size_t)bh * 80 + 64) * 1024 + s] = (f16)t;
        }
      }
    }
    return;
  } else if (EPI == 2) {
#pragma unroll
    for (int i = 0; i < 2; i++) {
#pragma unroll
      for (int r = 0; r < 4; r++) {
        int row = m0 + wm * 32 + i * 16 + l4 * 4 + r;
        float ss = 0.f;
#pragma unroll
        for (int j = 0; j < FN; j++) {
          int col = n0 + wn * (FN * 16) + j * 16 + l15;
          float gg = 0.f;
          if (col < 2047) {
            float yv = acc[i][j][r] + c0[col];
            float cc = yv * yv * yv;
            gg = 0.5f * yv * (1.f + tanhf(0.7978845608f * (yv + 0.044715f * cc)));
          }
          ss += gg * gg;
          H1[(size_t)row * 2048 + col] = (f16)gg;
        }
        ss += __shfl_xor(ss, 1); ss += __shfl_xor(ss, 2);
        ss += __shfl_xor(ss, 4); ss += __shfl_xor(ss, 8);
        if (l15 == 0) atomicAdd(ssq + row, ss);
      }
    }
    return;
  } else if (EPI == 3) {
    float* O = (tz == 0) ? O1 : (tz == 1) ? O2 : (tz == 2) ? O3 : O4;
#pragma unroll
    for (int i = 0; i < 2; i++) {
#pragma unroll
      for (int r = 0; r < 4; r++) {
        int row = m0 + wm * 32 + i * 16 + l4 * 4 + r;
        float t = 0.f;
        if (tz == 0) t = sqrtf(ssq[row] + 1.f);
#pragma unroll
        for (int j = 0; j < FN; j++) {
          int col = n0 + wn * (FN * 16) + j * 16 + l15;
          float v = acc[i][j][r];
          if (tz == 0) v += t * ((col < 511) ? c0[col] : 0.f);
          st4c(&O[(size_t)row * ldc + col], v);
        }
      }
    }
  } else {  // EPI 4 / 5: full store, sc0sc1
#pragma unroll
    for (int i = 0; i < 2; i++) {
      int row0 = m0 + wm * 32 + i * 16 + l4 * 4;
#pragma unroll
      for (int j = 0; j < FN; j++) {
        int col = n0 + wn * (FN * 16) + j * 16 + l15;
#pragma unroll
        for (int r = 0; r < 4; r++) st4c(&O1[(size_t)(row0 + r) * ldc + col], acc[i][j][r]);
      }
    }
  }
  // ---- last-arriver reduction (EPI 3/4/5) ----
  asm volatile("s_waitcnt vmcnt(0)" ::: "memory");
  __syncthreads();
  if (tid == 0) {
    u32 old = inc_rlx(cnt + tm);
    const u32 C = (EPI == 3) ? 32u : 8u;
    sred = ((old % C) == C - 1u);
  }
  __syncthreads();
  if (!sred) return;
  if (EPI == 3)
    reduce_tile<4, 0>(m0, O1, O2, O3, O4, c1, rwv[li], lng, lnb, x, act, nullptr, ssq, applyLN);
  else if (EPI == 4)
    reduce_tile<1, 0>(m0, O1, nullptr, nullptr, nullptr, c0, rwv[li], lng, lnb, x, act,
                      nullptr, nullptr, 1);
  else
    reduce_tile<1, 1>(m0, O1, nullptr, nullptr, nullptr, c0, 0.f, lng, lnb, nullptr, nullptr,
                      outp, nullptr, 0);
}

// ---------------- merged prologue: all weight transposes + cnt zero + embed ----------------
DEV void trans_tile1(const float* W, f16* BT, int K, int N, int ldk, int n0, int k0,
                     float* shbuf) {
  float (*tile)[33] = (float(*)[33])shbuf;
  int tx = threadIdx.x & 31, ty = threadIdx.x >> 5;
  for (int i = ty; i < 32; i += 8) {
    int k = k0 + i, n = n0 + tx;
    tile[i][tx] = (k < K && n < N) ? W[(size_t)k * N + n] : 0.f;
  }
  __syncthreads();
  for (int i = ty; i < 32; i += 8)
    BT[(size_t)(n0 + i) * ldk + k0 + tx] = (f16)tile[tx][i];
}

DEV float block_sum1(float v, float* red) {
#pragma unroll
  for (int o = 32; o; o >>= 1) v += __shfl_xor(v, o);
  int w = threadIdx.x >> 6;
  __syncthreads();
  if ((threadIdx.x & 63) == 0) red[w] = v;
  __syncthreads();
  return red[0] + red[1] + red[2] + red[3];
}

__global__ __launch_bounds__(256)
void k_prolog(const float* __restrict__ Wq, const float* __restrict__ Wk,
              const float* __restrict__ Wv, const float* __restrict__ Wo,
              const float* __restrict__ Wfc, const float* __restrict__ Wpr,
              const float* __restrict__ Wfin,
              f16* __restrict__ wqkvT, f16* __restrict__ woT, f16* __restrict__ wfcT,
              f16* __restrict__ wprT, f16* __restrict__ wfinT,
              const int* __restrict__ tok, const float* __restrict__ etab,
              const float* __restrict__ g, const float* __restrict__ bsh,
              float* __restrict__ x, f16* __restrict__ act, float* __restrict__ ssq,
              u32* __restrict__ cnt) {
  __shared__ float shbuf[32 * 33];
  const int bid = blockIdx.x, tid = threadIdx.x;
  if (bid == 0 && tid < 96) cnt[tid] = 0;
  if (bid < 9216) {
    int mat = bid >> 8, tile = bid & 255;
    int layer = mat / 3, typ = mat % 3;
    const float* W = ((typ == 0) ? Wq : (typ == 1) ? Wk : Wv) + (size_t)layer * 262144;
    f16* D = wqkvT + (size_t)layer * 786432 + (size_t)typ * 262144;
    trans_tile1(W, D, 512, 512, 512, (tile & 15) * 32, (tile >> 4) * 32, shbuf);
  } else if (bid < 12672) {
    int id = bid - 9216; int l = id / 288, t = id % 288;
    trans_tile1(Wo + (size_t)l * 265720, woT + (size_t)l * 294912, 520, 511, 576,
                (t % 16) * 32, (t / 16) * 32, shbuf);
  } else if (bid < 24960) {
    int id = bid - 12672; int l = id >> 10, t = id & 1023;
    trans_tile1(Wfc + (size_t)l * 1048064, wfcT + (size_t)l * 1048576, 512, 2047, 512,
                (t % 64) * 32, (t / 64) * 32, shbuf);
  } else if (bid < 37248) {
    int id = bid - 24960; int l = id >> 10, t = id & 1023;
    trans_tile1(Wpr + (size_t)l * 1046528 + 511, wprT + (size_t)l * 1048576, 2047, 511, 2048,
                (t & 15) * 32, (t >> 4) * 32, shbuf);
  } else if (bid < 37504) {
    int id = bid - 37248;
    trans_tile1(Wfin, wfinT, 512, 511, 512, (id & 15) * 32, (id >> 4) * 32, shbuf);
  } else {
    // embed + add_time + LN1 for one row
    float* red = shbuf;
    const int m = bid - 37504;
    const float* e = etab + (size_t)tok[m] * 511;
    float e0 = (tid < 511) ? e[tid] : 0.f;
    float e1 = (tid + 256 < 511) ? e[tid + 256] : 0.f;
    float s1 = block_sum1(e0 + e1, red);
    float s2 = block_sum1(e0 * e0 + e1 * e1, red);
    float t = sqrtf(s2 + 1.f);
    float* xr = x + (size_t)m * 512;
    if (tid == 0) { xr[0] = t; ssq[m] = 0.f; }
    if (tid < 511) xr[1 + tid] = e0;
    if (tid + 256 < 511) xr[257 + tid] = e1;
    float mu = s1 / 511.f;
    float var = s2 / 511.f - mu * mu;
    float inv = rsqrtf(var + 1e-5f);
    float n0 = (tid < 511) ? (e0 - mu) * inv * g[tid] + bsh[tid] : 0.f;
    float n1 = (tid + 256 < 511) ? (e1 - mu) * inv * g[tid + 256] + bsh[tid + 256] : 0.f;
    float sn = block_sum1(n0 * n0 + n1 * n1, red);
    float t2 = sqrtf(sn + 1.f);
    f16* ar = act + (size_t)m * 512;
    if (tid == 0) ar[0] = (f16)t2;
    if (tid < 511) ar[1 + tid] = (f16)n0;
    if (tid + 256 < 511) ar[257 + tid] = (f16)n1;
  }
}

// ---------------- per-wave flash attention + l_project (unchanged from R8) ----------------
__launch_bounds__(64)
__global__ void k_attn(const f16* __restrict__ qhat, const f16* __restrict__ khat,
                       const f16* __restrict__ vT, f16* __restrict__ ao) {
  __shared__ f16 sP[16 * 88];
  const int lin = blockIdx.x;
  const int wg = (lin & 7) * 128 + (lin >> 3);
  const int bh = wg >> 6, rt = 63 - (wg & 63);
  const int lane = threadIdx.x, l15 = lane & 15, l4 = lane >> 4;
  const f16* qp = qhat + ((size_t)bh * 1024 + rt * 16) * 88;
  const f16* kp = khat + (size_t)bh * 1024 * 88;
  const f16* vp = vT + (size_t)bh * 80 * 1024;
  f16x8 qf0 = *(const f16x8*)(qp + l15 * 88 + l4 * 8);
  f16x8 qf1 = *(const f16x8*)(qp + l15 * 88 + 32 + l4 * 8);
  float qth[4];
#pragma unroll
  for (int r = 0; r < 4; r++) qth[r] = (float)qp[(l4 * 4 + r) * 88 + 64];
  f32x4 acc[5];
#pragma unroll
  for (int i = 0; i < 5; i++) acc[i] = (f32x4){0, 0, 0, 0};
  float mrun[4] = {-3e38f, -3e38f, -3e38f, -3e38f}, lrun[4] = {0, 0, 0, 0};
  const int nt = (rt >> 2) + 1;
  for (int jt = 0; jt < nt; ++jt) {
    const int j0 = jt * 64;
    const bool dt = (jt == nt - 1);
    f32x4 sc[4];
#pragma unroll
    for (int fn = 0; fn < 4; fn++) {
      const f16* kb = kp + (size_t)(j0 + fn * 16 + l15) * 88;
      f16x8 k0v = *(const f16x8*)(kb + l4 * 8);
      f16x8 k1v = *(const f16x8*)(kb + 32 + l4 * 8);
      f32x4 a = (f32x4){0, 0, 0, 0};
      a = __builtin_amdgcn_mfma_f32_16x16x32_f16(qf0, k0v, a, 0, 0, 0);
      a = __builtin_amdgcn_mfma_f32_16x16x32_f16(qf1, k1v, a, 0, 0, 0);
      sc[fn] = a;
    }
    float s[4][4];
#pragma unroll
    for (int fn = 0; fn < 4; fn++) {
      float ktc = (float)kp[(size_t)(j0 + fn * 16 + l15) * 88 + 64];
      int col = j0 + fn * 16 + l15;
#pragma unroll
      for (int r = 0; r < 4; r++) {
        int row = rt * 16 + l4 * 4 + r;
        float v = sc[fn][r] - qth[r] * ktc;
        s[fn][r] = (!dt || col <= row) ? v : -3e38f;
      }
    }
    float mnew[4], al[4], rs[4];
#pragma unroll
    for (int r = 0; r < 4; r++) {
      float t = fmaxf(fmaxf(s[0][r], s[1][r]), fmaxf(s[2][r], s[3][r]));
#pragma unroll
      for (int o = 8; o; o >>= 1) t = fmaxf(t, __shfl_xor(t, o));
      mnew[r] = fmaxf(mrun[r], t);
      al[r] = exp2f((mrun[r] - mnew[r]) * 1.44269504f);
      mrun[r] = mnew[r];
      rs[r] = 0.f;
    }
#pragma unroll
    for (int fn = 0; fn < 4; fn++)
#pragma unroll
      for (int r = 0; r < 4; r++) {
        float p = exp2f((s[fn][r] - mnew[r]) * 1.44269504f);
        rs[r] += p;
        sP[(l4 * 4 + r) * 88 + fn * 16 + l15] = (f16)p;
      }
#pragma unroll
    for (int r = 0; r < 4; r++) {
#pragma unroll
      for (int o = 8; o; o >>= 1) rs[r] += __shfl_xor(rs[r], o);
      lrun[r] = lrun[r] * al[r] + rs[r];
    }
#pragma unroll
    for (int fd = 0; fd < 5; fd++)
#pragma unroll
      for (int r = 0; r < 4; r++) acc[fd][r] *= al[r];
    asm volatile("s_waitcnt lgkmcnt(0)" ::: "memory");
    __builtin_amdgcn_sched_barrier(0);
#pragma unroll
    for (int ks = 0; ks < 2; ks++) {
      f16x8 pf = *(const f16x8*)(sP + l15 * 88 + ks * 32 + l4 * 8);
#pragma unroll
      for (int fd = 0; fd < 5; fd++) {
        f16x8 vf = *(const f16x8*)(vp + (size_t)(fd * 16 + l15) * 1024 + j0 + ks * 32 + l4 * 8);
        acc[fd] = __builtin_amdgcn_mfma_f32_16x16x32_f16(pf, vf, acc[fd], 0, 0, 0);
      }
    }
  }
  const int b = bh >> 3, h = bh & 7;
#pragma unroll
  for (int r = 0; r < 4; r++) {
    float invl = 1.0f / lrun[r];
    float ss = 0.f, ov[4];
#pragma unroll
    for (int fd = 0; fd < 4; fd++) { ov[fd] = acc[fd][r] * invl; ss += ov[fd] * ov[fd]; }
#pragma unroll
    for (int o = 8; o; o >>= 1) ss += __shfl_xor(ss, o);
    float tv = acc[4][r] * invl;
    tv = __shfl(tv, lane & 48);
    float scp = rsqrtf(fmaxf(tv * tv - ss, 1e-6f));
    int row = rt * 16 + l4 * 4 + r;
    size_t rowbase = ((size_t)b * 1024 + row) * 576;
    size_t rb = rowbase + h * 65;
    if (l15 == 0) ao[rb] = (f16)(tv * scp);
#pragma unroll
    for (int fd = 0; fd < 4; fd++) ao[rb + 1 + fd * 16 + l15] = (f16)(ov[fd] * scp);
    for (int c = l15; c < 56; c += 16) ao[rowbase + 520 + c] = (f16)0.f;
  }
}

extern "C" void kernel_launch(void* const* d_in, const int* in_sizes, int n_in,
                              void* d_out, int out_size, void* d_ws, size_t ws_size,
                              hipStream_t stream) {
  (void)in_sizes; (void)n_in; (void)out_size; (void)ws_size;
  const int* tok = (const int*)d_in[0];
  const float* etab = (const float*)d_in[1];
  const float* Wq = (const float*)d_in[2];
  const float* bq = (const float*)d_in[3];
  const float* Wk = (const float*)d_in[4];
  const float* bk = (const float*)d_in[5];
  const float* Wv = (const float*)d_in[6];
  const float* bv = (const float*)d_in[7];
  const float* Wo = (const float*)d_in[8];
  const float* bo = (const float*)d_in[9];
  const float* ln1g = (const float*)d_in[10];
  const float* ln1b = (const float*)d_in[11];
  const float* ln2g = (const float*)d_in[12];
  const float* ln2b = (const float*)d_in[13];
  const float* Wfc = (const float*)d_in[14];
  const float* bfc = (const float*)d_in[15];
  const float* Wpr = (const float*)d_in[16];
  const float* bpr = (const float*)d_in[17];
  const float* rw1 = (const float*)d_in[18];
  const float* rw2 = (const float*)d_in[19];
  const float* Wfin = (const float*)d_in[20];
  const float* bfin = (const float*)d_in[21];
  const float* lnfg = (const float*)d_in[22];
  const float* lnfb = (const float*)d_in[23];

  char* wsb = (char*)d_ws;
  size_t off = 0;
  auto alloc = [&](size_t bytes) -> char* {
    char* p = wsb + off;
    off = (off + bytes + 1023) & ~(size_t)1023;
    return p;
  };
  float* x = (float*)alloc(2048ull * 512 * 4 + 1024);
  f16* actA = (f16*)alloc(2048ull * 512 * 2);
  float* raw1 = (float*)alloc(2048ull * 512 * 4);
  float* raw2 = (float*)alloc(2048ull * 512 * 4);
  float* raw3 = (float*)alloc(2048ull * 512 * 4);
  float* raw4 = (float*)alloc(2048ull * 512 * 4);
  float* ssq = (float*)alloc(2048ull * 4);
  f16* qhat = (f16*)alloc(16ull * 1024 * 88 * 2);
  f16* khat = (f16*)alloc(16ull * 1024 * 88 * 2);
  f16* vT = (f16*)alloc(16ull * 80 * 1024 * 2);
  f16* ao = (f16*)alloc(2048ull * 576 * 2);
  f16* fcact = (f16*)alloc(2048ull * 2048 * 2);
  f16* wqkvT = (f16*)alloc(12ull * 1536 * 512 * 2);
  f16* woT = (f16*)alloc(12ull * 512 * 576 * 2);
  f16* wfcT = (f16*)alloc(12ull * 2048 * 512 * 2);
  f16* wprT = (f16*)alloc(12ull * 512 * 2048 * 2);
  f16* wfinT = (f16*)alloc(512ull * 512 * 2);
  u32* cnt = (u32*)alloc(512);

  // prologue: all transposes + cnt zero + embed (1 launch)
  k_prolog<<<39552, 256, 0, stream>>>(Wq, Wk, Wv, Wo, Wfc, Wpr, Wfin,
                                      wqkvT, woT, wfcT, wprT, wfinT,
                                      tok, etab, ln1g, ln1b, x, actA, ssq, cnt);

  for (int li = 0; li < 12; li++) {
    const f16* wqkvT_l = wqkvT + (size_t)li * 1536 * 512;
    const f16* woT_l = woT + (size_t)li * 512 * 576;
    const f16* wfcT_l = wfcT + (size_t)li * 2048 * 512;
    const f16* wprT_l = wprT + (size_t)li * 512 * 2048;
    const float* Wpr_l = Wpr + (size_t)li * 2048 * 511;
    const float* bq_l = bq + (size_t)li * 512;
    const float* bk_l = bk + (size_t)li * 512;
    const float* bv_l = bv + (size_t)li * 512;
    const float* bo_l = bo + (size_t)li * 511;
    const float* bfc_l = bfc + (size_t)li * 2047;
    const float* bpr_l = bpr + (size_t)li * 511;
    const float* ln2g_l = ln2g + (size_t)li * 511;
    const float* ln2b_l = ln2b + (size_t)li * 511;
    const float* ng = (li < 11) ? ln1g + (size_t)(li + 1) * 511 : ln1g;
    const float* nb = (li < 11) ? ln1b + (size_t)(li + 1) * 511 : ln1b;

    // QKV: 128^2, 192 blocks x 512
    k_gemm<128, 128, 1, 1><<<192, 512, 0, stream>>>(
        actA, wqkvT_l, 512, 512, 512, 16, nullptr, nullptr, nullptr, nullptr, 0,
        bq_l, bk_l, bv_l, nullptr, qhat, khat, vT,
        nullptr, nullptr, nullptr, nullptr, nullptr, nullptr, 0, 0, nullptr);
    k_attn<<<1024, 64, 0, stream>>>(qhat, khat, vT, ao);
    // Wo + fused res1/LN2: 64^2, 256 blocks
    k_gemm<64, 64, 1, 4><<<256, 256, 0, stream>>>(
        ao, woT_l, 576, 576, 576, 32, raw1, nullptr, nullptr, nullptr, 512,
        bo_l, nullptr, nullptr, nullptr, nullptr, nullptr, nullptr,
        x, actA, nullptr, ln2g_l, ln2b_l, rw1, li, 1, cnt);
    // FC + gelu: 128^2, 256 blocks x 512
    k_gemm<128, 128, 1, 2><<<256, 512, 0, stream>>>(
        actA, wfcT_l, 512, 512, 512, 16, nullptr, nullptr, nullptr, nullptr, 0,
        bfc_l, nullptr, nullptr, ssq, fcact, nullptr, nullptr,
        nullptr, nullptr, nullptr, nullptr, nullptr, nullptr, 0, 0, nullptr);
    // Wpr split-K4 + fused res2/LN1(next): 64^2, 1024 blocks
    k_gemm<64, 64, 4, 3><<<1024, 256, 0, stream>>>(
        fcact, wprT_l, 2048, 2048, 512, 32, raw1, raw2, raw3, raw4, 512,
        Wpr_l, bpr_l, nullptr, ssq, nullptr, nullptr, nullptr,
        x, actA, nullptr, ng, nb, rw2, li, (li < 11) ? 1 : 0, cnt + 32);
  }

  // Wfin + fused final LN -> out
  k_gemm<64, 64, 1, 5><<<256, 256, 0, stream>>>(
      actA, wfinT, 512, 512, 512, 32, raw1, nullptr, nullptr, nullptr, 512,
      bfin, nullptr, nullptr, nullptr, nullptr, nullptr, nullptr,
      nullptr, nullptr, (float*)d_out, lnfg, lnfb, nullptr, 0, 0, cnt + 64);
}

// Round 10
// 2280.270 us; speedup vs baseline: 1.6538x; 1.6538x over previous
//
#include <hip/hip_runtime.h>
#include <cstdint>

typedef _Float16 f16;
typedef _Float16 f16x8 __attribute__((ext_vector_type(8)));
typedef float f32x4 __attribute__((ext_vector_type(4)));
typedef unsigned int u32;

#define DEV __device__ __forceinline__

DEV void gll16(const void* g, void* l) {
  __builtin_amdgcn_global_load_lds((const __attribute__((address_space(1))) u32*)g,
                                   (__attribute__((address_space(3))) u32*)l, 16, 0, 0);
}

DEV float wsum(float v) {
#pragma unroll
  for (int o = 32; o; o >>= 1) v += __shfl_xor(v, o);
  return v;
}

// ---------------- GEMM: BK=64, dbuf LDS, raw s_barrier + counted vmcnt ----------------
// EPI 0: Oo[row*ldc+col]=acc   EPI 1: QKV -> qhat/khat/vT
// EPI 2: bias+gelu -> H1 + atomicAdd ssq   EPI 3: split-K partial -> O(tz), rank-1 on tz0
// PRO 0: none   PRO 1: res1 (y=O1+bias) fused prologue   PRO 2: res2 (y=O1+..+O4+bias)
// Prologue recomputes resproj for the block's own BM rows (redundant across tn,
// bit-identical -> benign races); tn==0 persists x_out / zeroes ssq.
template <int BM, int BN, int KZ, int EPI, int PRO>
__global__ __launch_bounds__((BM == 128) ? 512 : 256)
void k_gemm(const f16* A, const f16* __restrict__ B,
            int lda, int ldb, int klen, int GM,
            float* O1, float* O2, float* O3, float* O4, float* Oo, int ldc,
            const float* __restrict__ c0, const float* __restrict__ c1,
            const float* __restrict__ c2, float* __restrict__ ssq,
            f16* __restrict__ H1, f16* __restrict__ H2, f16* __restrict__ H3,
            const float* __restrict__ xin, float* __restrict__ xout,
            const float* __restrict__ prbias, const float* __restrict__ prg,
            const float* __restrict__ prb, const float* __restrict__ rwv, int pli,
            int applyLN, f16* actW) {
  constexpr int NW = (BM == 128) ? 8 : 4;
  constexpr int WM = (BM == 128) ? 4 : 2;
  constexpr int FN = BN / ((NW / WM) * 16);
  const int tid = threadIdx.x, wid = tid >> 6, lane = tid & 63;
  const int l15 = lane & 15, l4 = lane >> 4;
  const int wm = wid % WM, wn = wid / WM;
  const int nwg = gridDim.x;
  int lin = blockIdx.x;
  int wg = (lin & 7) * (nwg >> 3) + (lin >> 3);
  int tn = wg / (GM * KZ);
  int rem = wg - tn * (GM * KZ);
  int tm = rem / KZ, tz = rem - (rem / KZ) * KZ;
  const int m0 = tm * BM, n0 = tn * BN, kbeg = tz * klen, ksteps = klen / 64;
  __shared__ __align__(16) char SM[(BM + BN) * 256];

  // ---- fused resproj prologue ----
  if constexpr (PRO > 0) {
    const int rpw = BM / NW;
    const int cbase = lane * 8;
    const float rw = rwv[pli];
    const bool writer = (tn == 0);
    for (int t = 0; t < rpw; t++) {
      const int row = m0 + wid * rpw + t;
      const size_t rb = (size_t)row * 512 + cbase;
      f32x4 a0 = *(const f32x4*)(O1 + rb), a1 = *(const f32x4*)(O1 + rb + 4);
      float y[8];
#pragma unroll
      for (int j = 0; j < 4; j++) { y[j] = a0[j]; y[4 + j] = a1[j]; }
      if constexpr (PRO == 2) {
        f32x4 b0 = *(const f32x4*)(O2 + rb), b1 = *(const f32x4*)(O2 + rb + 4);
        f32x4 g0 = *(const f32x4*)(O3 + rb), g1 = *(const f32x4*)(O3 + rb + 4);
        f32x4 d0 = *(const f32x4*)(O4 + rb), d1 = *(const f32x4*)(O4 + rb + 4);
#pragma unroll
        for (int j = 0; j < 4; j++) {
          y[j] += b0[j] + g0[j] + d0[j];
          y[4 + j] += b1[j] + g1[j] + d1[j];
        }
      }
      float lss = 0.f;
#pragma unroll
      for (int j = 0; j < 8; j++) {
        int c = cbase + j;
        y[j] = (c < 511) ? (y[j] + prbias[c]) : 0.f;
        lss += y[j] * y[j];
      }
      float tax = sqrtf(wsum(lss) + 1.f);
      const float* xrow = xin + (size_t)row * 512;
      float xs[8];
#pragma unroll
      for (int j = 0; j < 8; j++) {
        int c = cbase + j;
        xs[j] = (c < 511) ? xrow[1 + c] : 0.f;
      }
      float xt = xrow[0];
      float u[8], lsu = 0.f, lsu2 = 0.f;
#pragma unroll
      for (int j = 0; j < 8; j++) {
        int c = cbase + j;
        u[j] = (c < 511) ? (xs[j] + rw * y[j]) : 0.f;
        lsu += u[j]; lsu2 += u[j] * u[j];
      }
      float su = wsum(lsu), su2 = wsum(lsu2);
      float ut = xt + rw * tax;
      float scp = rsqrtf(fmaxf(ut * ut - su2, 1e-6f));
      float nxt = ut * scp, nx[8];
#pragma unroll
      for (int j = 0; j < 8; j++) nx[j] = u[j] * scp;
      if (writer && xout) {
        float* xo = xout + (size_t)row * 512;
        if (lane == 0) xo[0] = nxt;
#pragma unroll
        for (int j = 0; j < 8; j++) { int c = cbase + j; if (c < 511) xo[1 + c] = nx[j]; }
      }
      if (PRO == 2 && writer && ssq != nullptr && lane == 0) ssq[row] = 0.f;
      f16* arow = actW + (size_t)row * 512;
      if (applyLN) {
        float mu = su * scp * (1.f / 511.f);
        float var = su2 * scp * scp * (1.f / 511.f) - mu * mu;
        float inv = rsqrtf(var + 1e-5f);
        float n[8], lsn = 0.f;
#pragma unroll
        for (int j = 0; j < 8; j++) {
          int c = cbase + j;
          n[j] = (c < 511) ? ((nx[j] - mu) * inv * prg[c] + prb[c]) : 0.f;
          lsn += n[j] * n[j];
        }
        float t2 = sqrtf(wsum(lsn) + 1.f);
        if (lane == 0) arow[0] = (f16)t2;
#pragma unroll
        for (int j = 0; j < 8; j++) { int c = cbase + j; if (c < 511) arow[1 + c] = (f16)n[j]; }
      } else {
        if (lane == 0) arow[0] = (f16)nxt;
#pragma unroll
        for (int j = 0; j < 8; j++) { int c = cbase + j; if (c < 511) arow[1 + c] = (f16)nx[j]; }
      }
    }
    asm volatile("s_waitcnt vmcnt(0)" ::: "memory");
    __builtin_amdgcn_sched_barrier(0);
    __syncthreads();  // block's act stores visible in its L2 before gll16 staging
  }

  f32x4 acc[2][FN];
#pragma unroll
  for (int i = 0; i < 2; i++)
#pragma unroll
    for (int j = 0; j < FN; j++) acc[i][j] = (f32x4){0.f, 0.f, 0.f, 0.f};
  const size_t ldab = (size_t)lda * 2, ldbb = (size_t)ldb * 2;
  const int swz = ((lane & 7) ^ (lane >> 3)) * 16;
  const char* Ab = (const char*)A + (size_t)(m0 + (lane >> 3)) * ldab + swz + (size_t)kbeg * 2;
  const char* Bb = (const char*)B + (size_t)(n0 + (lane >> 3)) * ldbb + swz + (size_t)kbeg * 2;
  auto stage = [&](int buf, int ks) {
    char* da = SM + buf * (BM * 128);
    char* db = SM + 2 * BM * 128 + buf * (BN * 128);
    for (int i = wid; i < BM / 8; i += NW)
      gll16(Ab + (size_t)(i * 8) * ldab + (size_t)ks * 128, da + i * 1024);
    for (int i = wid; i < BN / 8; i += NW)
      gll16(Bb + (size_t)(i * 8) * ldbb + (size_t)ks * 128, db + i * 1024);
  };
  stage(0, 0);
  asm volatile("s_waitcnt vmcnt(0)" ::: "memory");
  __builtin_amdgcn_s_barrier();
  __builtin_amdgcn_sched_barrier(0);
  int cur = 0;
  for (int ks = 0; ks < ksteps; ks++) {
    const bool more = (ks + 1 < ksteps);
    if (more) {
      stage(cur ^ 1, ks + 1);
      asm volatile("s_waitcnt vmcnt(4)" ::: "memory");
    } else {
      asm volatile("s_waitcnt vmcnt(0)" ::: "memory");
    }
    __builtin_amdgcn_s_barrier();
    __builtin_amdgcn_sched_barrier(0);
    const f16* sA = (const f16*)(SM + cur * (BM * 128));
    const f16* sB = (const f16*)(SM + 2 * BM * 128 + cur * (BN * 128));
#pragma unroll
    for (int kk = 0; kk < 2; kk++) {
      f16x8 af[2], bf[FN];
#pragma unroll
      for (int i = 0; i < 2; i++) {
        int row = wm * 32 + i * 16 + l15;
        af[i] = *(const f16x8*)(sA + row * 64 + (((kk * 4 + l4) ^ (l15 & 7)) * 8));
      }
#pragma unroll
      for (int j = 0; j < FN; j++) {
        int row = wn * (FN * 16) + j * 16 + l15;
        bf[j] = *(const f16x8*)(sB + row * 64 + (((kk * 4 + l4) ^ (l15 & 7)) * 8));
      }
#pragma unroll
      for (int i = 0; i < 2; i++)
#pragma unroll
        for (int j = 0; j < FN; j++)
          acc[i][j] = __builtin_amdgcn_mfma_f32_16x16x32_f16(af[i], bf[j], acc[i][j], 0, 0, 0);
    }
    __builtin_amdgcn_sched_barrier(0);
    __builtin_amdgcn_s_barrier();
    cur ^= 1;
  }
  // ---- epilogues ----
  if (EPI == 0) {
#pragma unroll
    for (int i = 0; i < 2; i++) {
      int row0 = m0 + wm * 32 + i * 16 + l4 * 4;
#pragma unroll
      for (int j = 0; j < FN; j++) {
        int col = n0 + wn * (FN * 16) + j * 16 + l15;
#pragma unroll
        for (int r = 0; r < 4; r++) Oo[(size_t)(row0 + r) * ldc + col] = acc[i][j][r];
      }
    }
  } else if (EPI == 1) {
    const int cb = (n0 >> 6) + wn;
    const int typ = cb >> 3, h = cb & 7;
    const float* bb = (typ == 0) ? c0 : (typ == 1) ? c1 : c2;
    float bj[FN];
#pragma unroll
    for (int j = 0; j < FN; j++) bj[j] = bb[h * 64 + j * 16 + l15];
    const float qs = (typ == 0) ? 0.25f : 1.0f;
#pragma unroll
    for (int i = 0; i < 2; i++) {
#pragma unroll
      for (int r = 0; r < 4; r++) {
        float y[FN], ss = 0.f;
#pragma unroll
        for (int j = 0; j < FN; j++) { y[j] = acc[i][j][r] + bj[j]; ss += y[j] * y[j]; }
        ss += __shfl_xor(ss, 1); ss += __shfl_xor(ss, 2);
        ss += __shfl_xor(ss, 4); ss += __shfl_xor(ss, 8);
        float t = sqrtf(ss + 1.f);
        int row = m0 + wm * 32 + i * 16 + l4 * 4 + r;
        int b = row >> 10, s = row & 1023, bh = b * 8 + h;
        if (typ < 2) {
          f16* dst = typ ? H2 : H1;
          size_t base = ((size_t)bh * 1024 + s) * 88;
#pragma unroll
          for (int j = 0; j < FN; j++) dst[base + j * 16 + l15] = (f16)(qs * y[j]);
          if (l15 == 0) dst[base + 64] = (f16)(qs * t);
        } else {
#pragma unroll
          for (int j = 0; j < FN; j++)
            H3[((size_t)bh * 80 + j * 16 + l15) * 1024 + s] = (f16)y[j];
          if (l15 == 0) H3[((size_t)bh * 80 + 64) * 1024 + s] = (f16)t;
        }
      }
    }
  } else if (EPI == 2) {
#pragma unroll
    for (int i = 0; i < 2; i++) {
#pragma unroll
      for (int r = 0; r < 4; r++) {
        int row = m0 + wm * 32 + i * 16 + l4 * 4 + r;
        float ss = 0.f;
#pragma unroll
        for (int j = 0; j < FN; j++) {
          int col = n0 + wn * (FN * 16) + j * 16 + l15;
          float gg = 0.f;
          if (col < 2047) {
            float yv = acc[i][j][r] + c0[col];
            float cc = yv * yv * yv;
            gg = 0.5f * yv * (1.f + tanhf(0.7978845608f * (yv + 0.044715f * cc)));
          }
          ss += gg * gg;
          H1[(size_t)row * 2048 + col] = (f16)gg;
        }
        ss += __shfl_xor(ss, 1); ss += __shfl_xor(ss, 2);
        ss += __shfl_xor(ss, 4); ss += __shfl_xor(ss, 8);
        if (l15 == 0) atomicAdd(ssq + row, ss);
      }
    }
  } else {  // EPI == 3: split-K partial, plain stores
    float* O = (tz == 0) ? O1 : (tz == 1) ? O2 : (tz == 2) ? O3 : O4;
#pragma unroll
    for (int i = 0; i < 2; i++) {
#pragma unroll
      for (int r = 0; r < 4; r++) {
        int row = m0 + wm * 32 + i * 16 + l4 * 4 + r;
        float t = 0.f;
        if (tz == 0) t = sqrtf(ssq[row] + 1.f);
#pragma unroll
        for (int j = 0; j < FN; j++) {
          int col = n0 + wn * (FN * 16) + j * 16 + l15;
          float v = acc[i][j][r];
          if (tz == 0) v += t * ((col < 511) ? c0[col] : 0.f);
          O[(size_t)row * ldc + col] = v;
        }
      }
    }
  }
}

// ---------------- merged prologue: all weight transposes + embed ----------------
DEV void trans_tile1(const float* W, f16* BT, int K, int N, int ldk, int n0, int k0,
                     float* shbuf) {
  float (*tile)[33] = (float(*)[33])shbuf;
  int tx = threadIdx.x & 31, ty = threadIdx.x >> 5;
  for (int i = ty; i < 32; i += 8) {
    int k = k0 + i, n = n0 + tx;
    tile[i][tx] = (k < K && n < N) ? W[(size_t)k * N + n] : 0.f;
  }
  __syncthreads();
  for (int i = ty; i < 32; i += 8)
    BT[(size_t)(n0 + i) * ldk + k0 + tx] = (f16)tile[tx][i];
}

DEV float block_sum1(float v, float* red) {
#pragma unroll
  for (int o = 32; o; o >>= 1) v += __shfl_xor(v, o);
  int w = threadIdx.x >> 6;
  __syncthreads();
  if ((threadIdx.x & 63) == 0) red[w] = v;
  __syncthreads();
  return red[0] + red[1] + red[2] + red[3];
}

__global__ __launch_bounds__(256)
void k_prolog(const float* __restrict__ Wq, const float* __restrict__ Wk,
              const float* __restrict__ Wv, const float* __restrict__ Wo,
              const float* __restrict__ Wfc, const float* __restrict__ Wpr,
              const float* __restrict__ Wfin,
              f16* __restrict__ wqkvT, f16* __restrict__ woT, f16* __restrict__ wfcT,
              f16* __restrict__ wprT, f16* __restrict__ wfinT,
              const int* __restrict__ tok, const float* __restrict__ etab,
              const float* __restrict__ g, const float* __restrict__ bsh,
              float* __restrict__ x, f16* __restrict__ act, float* __restrict__ ssq) {
  __shared__ float shbuf[32 * 33];
  const int bid = blockIdx.x, tid = threadIdx.x;
  if (bid < 9216) {
    int mat = bid >> 8, tile = bid & 255;
    int layer = mat / 3, typ = mat % 3;
    const float* W = ((typ == 0) ? Wq : (typ == 1) ? Wk : Wv) + (size_t)layer * 262144;
    f16* D = wqkvT + (size_t)layer * 786432 + (size_t)typ * 262144;
    trans_tile1(W, D, 512, 512, 512, (tile & 15) * 32, (tile >> 4) * 32, shbuf);
  } else if (bid < 12672) {
    int id = bid - 9216; int l = id / 288, t = id % 288;
    trans_tile1(Wo + (size_t)l * 265720, woT + (size_t)l * 294912, 520, 511, 576,
                (t % 16) * 32, (t / 16) * 32, shbuf);
  } else if (bid < 24960) {
    int id = bid - 12672; int l = id >> 10, t = id & 1023;
    trans_tile1(Wfc + (size_t)l * 1048064, wfcT + (size_t)l * 1048576, 512, 2047, 512,
                (t % 64) * 32, (t / 64) * 32, shbuf);
  } else if (bid < 37248) {
    int id = bid - 24960; int l = id >> 10, t = id & 1023;
    trans_tile1(Wpr + (size_t)l * 1046528 + 511, wprT + (size_t)l * 1048576, 2047, 511, 2048,
                (t & 15) * 32, (t >> 4) * 32, shbuf);
  } else if (bid < 37504) {
    int id = bid - 37248;
    trans_tile1(Wfin, wfinT, 512, 511, 512, (id & 15) * 32, (id >> 4) * 32, shbuf);
  } else {
    float* red = shbuf;
    const int m = bid - 37504;
    const float* e = etab + (size_t)tok[m] * 511;
    float e0 = (tid < 511) ? e[tid] : 0.f;
    float e1 = (tid + 256 < 511) ? e[tid + 256] : 0.f;
    float s1 = block_sum1(e0 + e1, red);
    float s2 = block_sum1(e0 * e0 + e1 * e1, red);
    float t = sqrtf(s2 + 1.f);
    float* xr = x + (size_t)m * 512;
    if (tid == 0) { xr[0] = t; ssq[m] = 0.f; }
    if (tid < 511) xr[1 + tid] = e0;
    if (tid + 256 < 511) xr[257 + tid] = e1;
    float mu = s1 / 511.f;
    float var = s2 / 511.f - mu * mu;
    float inv = rsqrtf(var + 1e-5f);
    float n0 = (tid < 511) ? (e0 - mu) * inv * g[tid] + bsh[tid] : 0.f;
    float n1 = (tid + 256 < 511) ? (e1 - mu) * inv * g[tid + 256] + bsh[tid + 256] : 0.f;
    float sn = block_sum1(n0 * n0 + n1 * n1, red);
    float t2 = sqrtf(sn + 1.f);
    f16* ar = act + (size_t)m * 512;
    if (tid == 0) ar[0] = (f16)t2;
    if (tid < 511) ar[1 + tid] = (f16)n0;
    if (tid + 256 < 511) ar[257 + tid] = (f16)n1;
  }
}

// ---------------- per-wave flash attention + l_project ----------------
__launch_bounds__(64)
__global__ void k_attn(const f16* __restrict__ qhat, const f16* __restrict__ khat,
                       const f16* __restrict__ vT, f16* __restrict__ ao) {
  __shared__ f16 sP[16 * 88];
  const int lin = blockIdx.x;
  const int wg = (lin & 7) * 128 + (lin >> 3);
  const int bh = wg >> 6, rt = 63 - (wg & 63);
  const int lane = threadIdx.x, l15 = lane & 15, l4 = lane >> 4;
  const f16* qp = qhat + ((size_t)bh * 1024 + rt * 16) * 88;
  const f16* kp = khat + (size_t)bh * 1024 * 88;
  const f16* vp = vT + (size_t)bh * 80 * 1024;
  f16x8 qf0 = *(const f16x8*)(qp + l15 * 88 + l4 * 8);
  f16x8 qf1 = *(const f16x8*)(qp + l15 * 88 + 32 + l4 * 8);
  float qth[4];
#pragma unroll
  for (int r = 0; r < 4; r++) qth[r] = (float)qp[(l4 * 4 + r) * 88 + 64];
  f32x4 acc[5];
#pragma unroll
  for (int i = 0; i < 5; i++) acc[i] = (f32x4){0, 0, 0, 0};
  float mrun[4] = {-3e38f, -3e38f, -3e38f, -3e38f}, lrun[4] = {0, 0, 0, 0};
  const int nt = (rt >> 2) + 1;
  for (int jt = 0; jt < nt; ++jt) {
    const int j0 = jt * 64;
    const bool dt = (jt == nt - 1);
    f32x4 sc[4];
#pragma unroll
    for (int fn = 0; fn < 4; fn++) {
      const f16* kb = kp + (size_t)(j0 + fn * 16 + l15) * 88;
      f16x8 k0v = *(const f16x8*)(kb + l4 * 8);
      f16x8 k1v = *(const f16x8*)(kb + 32 + l4 * 8);
      f32x4 a = (f32x4){0, 0, 0, 0};
      a = __builtin_amdgcn_mfma_f32_16x16x32_f16(qf0, k0v, a, 0, 0, 0);
      a = __builtin_amdgcn_mfma_f32_16x16x32_f16(qf1, k1v, a, 0, 0, 0);
      sc[fn] = a;
    }
    float s[4][4];
#pragma unroll
    for (int fn = 0; fn < 4; fn++) {
      float ktc = (float)kp[(size_t)(j0 + fn * 16 + l15) * 88 + 64];
      int col = j0 + fn * 16 + l15;
#pragma unroll
      for (int r = 0; r < 4; r++) {
        int row = rt * 16 + l4 * 4 + r;
        float v = sc[fn][r] - qth[r] * ktc;
        s[fn][r] = (!dt || col <= row) ? v : -3e38f;
      }
    }
    float mnew[4], al[4], rs[4];
#pragma unroll
    for (int r = 0; r < 4; r++) {
      float t = fmaxf(fmaxf(s[0][r], s[1][r]), fmaxf(s[2][r], s[3][r]));
#pragma unroll
      for (int o = 8; o; o >>= 1) t = fmaxf(t, __shfl_xor(t, o));
      mnew[r] = fmaxf(mrun[r], t);
      al[r] = exp2f((mrun[r] - mnew[r]) * 1.44269504f);
      mrun[r] = mnew[r];
      rs[r] = 0.f;
    }
#pragma unroll
    for (int fn = 0; fn < 4; fn++)
#pragma unroll
      for (int r = 0; r < 4; r++) {
        float p = exp2f((s[fn][r] - mnew[r]) * 1.44269504f);
        rs[r] += p;
        sP[(l4 * 4 + r) * 88 + fn * 16 + l15] = (f16)p;
      }
#pragma unroll
    for (int r = 0; r < 4; r++) {
#pragma unroll
      for (int o = 8; o; o >>= 1) rs[r] += __shfl_xor(rs[r], o);
      lrun[r] = lrun[r] * al[r] + rs[r];
    }
#pragma unroll
    for (int fd = 0; fd < 5; fd++)
#pragma unroll
      for (int r = 0; r < 4; r++) acc[fd][r] *= al[r];
    asm volatile("s_waitcnt lgkmcnt(0)" ::: "memory");
    __builtin_amdgcn_sched_barrier(0);
#pragma unroll
    for (int ks = 0; ks < 2; ks++) {
      f16x8 pf = *(const f16x8*)(sP + l15 * 88 + ks * 32 + l4 * 8);
#pragma unroll
      for (int fd = 0; fd < 5; fd++) {
        f16x8 vf = *(const f16x8*)(vp + (size_t)(fd * 16 + l15) * 1024 + j0 + ks * 32 + l4 * 8);
        acc[fd] = __builtin_amdgcn_mfma_f32_16x16x32_f16(pf, vf, acc[fd], 0, 0, 0);
      }
    }
  }
  const int b = bh >> 3, h = bh & 7;
#pragma unroll
  for (int r = 0; r < 4; r++) {
    float invl = 1.0f / lrun[r];
    float ss = 0.f, ov[4];
#pragma unroll
    for (int fd = 0; fd < 4; fd++) { ov[fd] = acc[fd][r] * invl; ss += ov[fd] * ov[fd]; }
#pragma unroll
    for (int o = 8; o; o >>= 1) ss += __shfl_xor(ss, o);
    float tv = acc[4][r] * invl;
    tv = __shfl(tv, lane & 48);
    float scp = rsqrtf(fmaxf(tv * tv - ss, 1e-6f));
    int row = rt * 16 + l4 * 4 + r;
    size_t rowbase = ((size_t)b * 1024 + row) * 576;
    size_t rb = rowbase + h * 65;
    if (l15 == 0) ao[rb] = (f16)(tv * scp);
#pragma unroll
    for (int fd = 0; fd < 4; fd++) ao[rb + 1 + fd * 16 + l15] = (f16)(ov[fd] * scp);
    for (int c = l15; c < 56; c += 16) ao[rowbase + 520 + c] = (f16)0.f;
  }
}

// ---------------- final bias + LN -> out ----------------
__global__ void k_final(const float* __restrict__ raw, const float* __restrict__ bias,
                        const float* __restrict__ g, const float* __restrict__ bsh,
                        float* __restrict__ out) {
  __shared__ float red[4];
  const int m = blockIdx.x, tid = threadIdx.x;
  const float* rr = raw + (size_t)m * 512;
  float y0 = (tid < 511) ? rr[tid] + bias[tid] : 0.f;
  float y1 = (tid + 256 < 511) ? rr[tid + 256] + bias[tid + 256] : 0.f;
  float s1 = block_sum1(y0 + y1, red);
  float s2 = block_sum1(y0 * y0 + y1 * y1, red);
  float mu = s1 / 511.f;
  float var = s2 / 511.f - mu * mu;
  float inv = rsqrtf(var + 1e-5f);
  float n0 = (tid < 511) ? (y0 - mu) * inv * g[tid] + bsh[tid] : 0.f;
  float n1 = (tid + 256 < 511) ? (y1 - mu) * inv * g[tid + 256] + bsh[tid + 256] : 0.f;
  float sn = block_sum1(n0 * n0 + n1 * n1, red);
  float t2 = sqrtf(sn + 1.f);
  float* orow = out + (size_t)m * 512;
  if (tid == 0) orow[0] = t2;
  if (tid < 511) orow[1 + tid] = n0;
  if (tid + 256 < 511) orow[257 + tid] = n1;
}

extern "C" void kernel_launch(void* const* d_in, const int* in_sizes, int n_in,
                              void* d_out, int out_size, void* d_ws, size_t ws_size,
                              hipStream_t stream) {
  (void)in_sizes; (void)n_in; (void)out_size; (void)ws_size;
  const int* tok = (const int*)d_in[0];
  const float* etab = (const float*)d_in[1];
  const float* Wq = (const float*)d_in[2];
  const float* bq = (const float*)d_in[3];
  const float* Wk = (const float*)d_in[4];
  const float* bk = (const float*)d_in[5];
  const float* Wv = (const float*)d_in[6];
  const float* bv = (const float*)d_in[7];
  const float* Wo = (const float*)d_in[8];
  const float* bo = (const float*)d_in[9];
  const float* ln1g = (const float*)d_in[10];
  const float* ln1b = (const float*)d_in[11];
  const float* ln2g = (const float*)d_in[12];
  const float* ln2b = (const float*)d_in[13];
  const float* Wfc = (const float*)d_in[14];
  const float* bfc = (const float*)d_in[15];
  const float* Wpr = (const float*)d_in[16];
  const float* bpr = (const float*)d_in[17];
  const float* rw1 = (const float*)d_in[18];
  const float* rw2 = (const float*)d_in[19];
  const float* Wfin = (const float*)d_in[20];
  const float* bfin = (const float*)d_in[21];
  const float* lnfg = (const float*)d_in[22];
  const float* lnfb = (const float*)d_in[23];

  char* wsb = (char*)d_ws;
  size_t off = 0;
  auto alloc = [&](size_t bytes) -> char* {
    char* p = wsb + off;
    off = (off + bytes + 1023) & ~(size_t)1023;
    return p;
  };
  float* xA = (float*)alloc(2048ull * 512 * 4);
  float* xB = (float*)alloc(2048ull * 512 * 4);
  f16* actQ = (f16*)alloc(2048ull * 512 * 2);
  f16* actF = (f16*)alloc(2048ull * 512 * 2);
  float* raw1 = (float*)alloc(2048ull * 512 * 4);
  float* raw2 = (float*)alloc(2048ull * 512 * 4);
  float* raw3 = (float*)alloc(2048ull * 512 * 4);
  float* raw4 = (float*)alloc(2048ull * 512 * 4);
  float* rawF = (float*)alloc(2048ull * 512 * 4);
  float* ssq = (float*)alloc(2048ull * 4);
  f16* qhat = (f16*)alloc(16ull * 1024 * 88 * 2);
  f16* khat = (f16*)alloc(16ull * 1024 * 88 * 2);
  f16* vT = (f16*)alloc(16ull * 80 * 1024 * 2);
  f16* ao = (f16*)alloc(2048ull * 576 * 2);
  f16* fcact = (f16*)alloc(2048ull * 2048 * 2);
  f16* wqkvT = (f16*)alloc(12ull * 1536 * 512 * 2);
  f16* woT = (f16*)alloc(12ull * 512 * 576 * 2);
  f16* wfcT = (f16*)alloc(12ull * 2048 * 512 * 2);
  f16* wprT = (f16*)alloc(12ull * 512 * 2048 * 2);
  f16* wfinT = (f16*)alloc(512ull * 512 * 2);

  k_prolog<<<39552, 256, 0, stream>>>(Wq, Wk, Wv, Wo, Wfc, Wpr, Wfin,
                                      wqkvT, woT, wfcT, wprT, wfinT,
                                      tok, etab, ln1g, ln1b, xA, actQ, ssq);

  for (int li = 0; li < 12; li++) {
    const f16* wqkvT_l = wqkvT + (size_t)li * 1536 * 512;
    const f16* woT_l = woT + (size_t)li * 512 * 576;
    const f16* wfcT_l = wfcT + (size_t)li * 2048 * 512;
    const f16* wprT_l = wprT + (size_t)li * 512 * 2048;
    const float* Wpr_l = Wpr + (size_t)li * 2048 * 511;
    const float* bq_l = bq + (size_t)li * 512;
    const float* bk_l = bk + (size_t)li * 512;
    const float* bv_l = bv + (size_t)li * 512;
    const float* bo_l = bo + (size_t)li * 511;
    const float* bfc_l = bfc + (size_t)li * 2047;
    const float* ln1g_l = ln1g + (size_t)li * 511;
    const float* ln1b_l = ln1b + (size_t)li * 511;
    const float* ln2g_l = ln2g + (size_t)li * 511;
    const float* ln2b_l = ln2b + (size_t)li * 511;

    // QKV (+ fused res2 of layer li-1 for li>=1)
    if (li == 0)
      k_gemm<128, 128, 1, 1, 0><<<192, 512, 0, stream>>>(
          actQ, wqkvT_l, 512, 512, 512, 16, nullptr, nullptr, nullptr, nullptr, nullptr, 0,
          bq_l, bk_l, bv_l, nullptr, qhat, khat, vT,
          nullptr, nullptr, nullptr, nullptr, nullptr, nullptr, 0, 0, nullptr);
    else
      k_gemm<128, 128, 1, 1, 2><<<192, 512, 0, stream>>>(
          actQ, wqkvT_l, 512, 512, 512, 16, raw1, raw2, raw3, raw4, nullptr, 0,
          bq_l, bk_l, bv_l, ssq, qhat, khat, vT,
          xB, xA, bpr + (size_t)(li - 1) * 511, ln1g_l, ln1b_l, rw2, li - 1, 1, actQ);
    k_attn<<<1024, 64, 0, stream>>>(qhat, khat, vT, ao);
    // Wo
    k_gemm<64, 64, 1, 0, 0><<<256, 256, 0, stream>>>(
        ao, woT_l, 576, 576, 576, 32, nullptr, nullptr, nullptr, nullptr, raw1, 512,
        nullptr, nullptr, nullptr, nullptr, nullptr, nullptr, nullptr,
        nullptr, nullptr, nullptr, nullptr, nullptr, nullptr, 0, 0, nullptr);
    // FC (+ fused res1/LN2)
    k_gemm<128, 128, 1, 2, 1><<<256, 512, 0, stream>>>(
        actF, wfcT_l, 512, 512, 512, 16, raw1, nullptr, nullptr, nullptr, nullptr, 0,
        bfc_l, nullptr, nullptr, ssq, fcact, nullptr, nullptr,
        xA, xB, bo_l, ln2g_l, ln2b_l, rw1, li, 1, actF);
    // Wpr split-K4 (+ rank-1 on tz0)
    k_gemm<64, 64, 4, 3, 0><<<1024, 256, 0, stream>>>(
        fcact, wprT_l, 2048, 2048, 512, 32, raw1, raw2, raw3, raw4, nullptr, 512,
        Wpr_l, nullptr, nullptr, ssq, nullptr, nullptr, nullptr,
        nullptr, nullptr, nullptr, nullptr, nullptr, nullptr, 0, 0, nullptr);
  }

  // Wfin (+ fused res2 of layer 11, no LN)
  k_gemm<64, 64, 1, 0, 2><<<256, 256, 0, stream>>>(
      actF, wfinT, 512, 512, 512, 32, raw1, raw2, raw3, raw4, rawF, 512,
      nullptr, nullptr, nullptr, nullptr, nullptr, nullptr, nullptr,
      xB, nullptr, bpr + 11ull * 511, nullptr, nullptr, rw2, 11, 0, actF);
  k_final<<<2048, 256, 0, stream>>>(rawF, bfin, lnfg, lnfb, (float*)d_out);
}